// Round 1
// baseline (92.227 us; speedup 1.0000x reference)
//
#include <hip/hip_runtime.h>
#include <math.h>

// NCC loss, restructured:
//   sum(cross)  = A - D/225,  A = sum I*J*cnt,  D = sum S_I*S_J
//   sum(I_var)  = B - E/225,  B = sum I*I*cnt,  E = sum S_I^2
//   sum(J_var)  = C - F/225,  C = sum J*J*cnt,  F = sum S_J^2
// where S_X = 15x15 zero-padded box sum of X, cnt(i,j) = ch(i)*cw(j),
// ch(i) = min(i,7)+min(511-i,7)+1.
//
// R4: horizontal-first in registers.
//  - stage 1: each thread owns (row r, 16-col segment k). Loads its 32-float
//    window per array as 8x float4 directly from global (rows are contiguous),
//    computes the horizontal 15-tap sliding sum in REGISTERS, writes only the
//    H sums to LDS (conflict-free b128, stride 68). A/B/C accumulated from the
//    same registers. Raw tiles never touch LDS.
//  - stage 2: vertical 15-tap slide over H: 64 cols x 4 row-chunks, stride-1
//    conflict-free b32 reads.
//  - LDS 50.5 KB -> 25.1 KB, barriers 3 -> 2, LDS ops/thread roughly halved.
//  - partials stored SoA [6][NBLK] so finalize reads coalesced float4.

#define IMG_H 512
#define IMG_W 512
#define NB    16
#define TW    64
#define TH    32
#define HR    46            // TH + 14 rows of horizontal sums
#define HSTR  68            // padded row stride (floats): b128-aligned, bank-spread
#define NTX   8             // 512/64
#define NTY   16            // 512/32
#define NBLK  (NB * NTX * NTY)   // 2048

__device__ __forceinline__ float winw(int i) {
    int a = i < 7 ? i : 7;
    int b = (511 - i) < 7 ? (511 - i) : 7;
    return (float)(a + b + 1);
}

__global__ __launch_bounds__(256, 4) void ncc_main(const float* __restrict__ I,
                                                   const float* __restrict__ J,
                                                   float* __restrict__ partials) {
    __shared__ float hI[HR * HSTR];
    __shared__ float hJ[HR * HSTR];
    __shared__ float red[4 * 6];

    const int tid = threadIdx.x;
    const int tx = blockIdx.x, ty = blockIdx.y, bz = blockIdx.z;
    const float* Ib = I + (size_t)bz * IMG_H * IMG_W;
    const float* Jb = J + (size_t)bz * IMG_H * IMG_W;

    float a0 = 0.f, a1 = 0.f, a2 = 0.f;

    // ---- stage 1: horizontal 15-tap sums in registers ----
    // thread (r = tid>>2, k = tid&3): row r of the 46-row band, cols 16k..16k+15.
    // Window: 32 floats starting at tile col 16k-8 (float4-aligned in the image).
    {
        int r = tid >> 2;
        int k = tid & 3;
        if (r < HR) {
            int gr = ty * TH - 7 + r;
            int cb = tx * TW + 16 * k - 8;      // multiple of 4
            bool rok = (unsigned)gr < (unsigned)IMG_H;
            const float* Irow = Ib + gr * IMG_W;
            const float* Jrow = Jb + gr * IMG_W;

            float xI[32], xJ[32];
            #pragma unroll
            for (int i = 0; i < 8; ++i) {
                int gc = cb + 4 * i;
                float4 iv = make_float4(0.f, 0.f, 0.f, 0.f);
                float4 jv = make_float4(0.f, 0.f, 0.f, 0.f);
                if (rok && (unsigned)gc < (unsigned)IMG_W) {
                    iv = *reinterpret_cast<const float4*>(Irow + gc);
                    jv = *reinterpret_cast<const float4*>(Jrow + gc);
                }
                xI[4 * i + 0] = iv.x; xI[4 * i + 1] = iv.y;
                xI[4 * i + 2] = iv.z; xI[4 * i + 3] = iv.w;
                xJ[4 * i + 0] = jv.x; xJ[4 * i + 1] = jv.y;
                xJ[4 * i + 2] = jv.z; xJ[4 * i + 3] = jv.w;
            }

            // H[j] (output col 16k+j) = sum of x[j+1 .. j+15]
            float sI = 0.f, sJ = 0.f;
            #pragma unroll
            for (int m = 1; m <= 15; ++m) { sI += xI[m]; sJ += xJ[m]; }

            float* hIp = hI + r * HSTR + 16 * k;
            float* hJp = hJ + r * HSTR + 16 * k;
            #pragma unroll
            for (int t = 0; t < 4; ++t) {
                float4 bI, bJ;
                #pragma unroll
                for (int u = 0; u < 4; ++u) {
                    int j = 4 * t + u;
                    if (j > 0) {
                        sI += xI[j + 15] - xI[j];
                        sJ += xJ[j + 15] - xJ[j];
                    }
                    (&bI.x)[u] = sI;
                    (&bJ.x)[u] = sJ;
                }
                *reinterpret_cast<float4*>(hIp + 4 * t) = bI;
                *reinterpret_cast<float4*>(hJp + 4 * t) = bJ;
            }

            // A/B/C from registers: interior rows are r in [7, 7+TH)
            if (r >= 7 && r < 7 + TH) {
                float wr = winw(gr);
                float p0 = 0.f, p1 = 0.f, p2 = 0.f;
                #pragma unroll
                for (int j = 0; j < 16; ++j) {
                    float wc = winw(tx * TW + 16 * k + j);
                    float Iv = xI[j + 8];
                    float Jv = xJ[j + 8];
                    p0 += Iv * Jv * wc;
                    p1 += Iv * Iv * wc;
                    p2 += Jv * Jv * wc;
                }
                a0 += wr * p0;
                a1 += wr * p1;
                a2 += wr * p2;
            }
        }
    }
    __syncthreads();

    // ---- stage 2: vertical 15-tap slide over H (stride-1, conflict-free) ----
    float a3 = 0.f, a4 = 0.f, a5 = 0.f;
    {
        int col = tid & 63;
        int chunk = tid >> 6;       // 4 chunks x 8 output rows
        int c8 = chunk * 8;
        const float* pI = hI + c8 * HSTR + col;
        const float* pJ = hJ + c8 * HSTR + col;
        float sI = 0.f, sJ = 0.f;
        #pragma unroll
        for (int dr = 0; dr < 15; ++dr) {
            sI += pI[dr * HSTR];
            sJ += pJ[dr * HSTR];
        }
        a3 += sI * sJ; a4 += sI * sI; a5 += sJ * sJ;
        #pragma unroll
        for (int s = 1; s < 8; ++s) {
            sI += pI[(14 + s) * HSTR] - pI[(s - 1) * HSTR];
            sJ += pJ[(14 + s) * HSTR] - pJ[(s - 1) * HSTR];
            a3 += sI * sJ; a4 += sI * sI; a5 += sJ * sJ;
        }
    }

    // ---- block reduction: wave shuffle then LDS across the 4 waves ----
    float vals[6] = {a0, a1, a2, a3, a4, a5};
    #pragma unroll
    for (int k = 0; k < 6; ++k) {
        float v = vals[k];
        #pragma unroll
        for (int off = 32; off > 0; off >>= 1) v += __shfl_down(v, off, 64);
        vals[k] = v;
    }
    int wave = tid >> 6, lane = tid & 63;
    if (lane == 0) {
        #pragma unroll
        for (int k = 0; k < 6; ++k) red[wave * 6 + k] = vals[k];
    }
    __syncthreads();
    if (tid == 0) {
        int bidx = (bz * NTY + ty) * NTX + tx;
        #pragma unroll
        for (int k = 0; k < 6; ++k) {
            partials[k * NBLK + bidx] = red[k] + red[6 + k] + red[12 + k] + red[18 + k];
        }
    }
}

__global__ __launch_bounds__(256) void ncc_finalize(const float* __restrict__ partials,
                                                    float* __restrict__ out) {
    __shared__ double red[4 * 6];
    int tid = threadIdx.x;
    double acc[6] = {0, 0, 0, 0, 0, 0};
    #pragma unroll
    for (int k = 0; k < 6; ++k) {
        const float4* p = reinterpret_cast<const float4*>(partials + k * NBLK);
        for (int t = tid; t < NBLK / 4; t += 256) {
            float4 v = p[t];
            acc[k] += (double)v.x + (double)v.y + (double)v.z + (double)v.w;
        }
    }
    #pragma unroll
    for (int k = 0; k < 6; ++k) {
        double v = acc[k];
        #pragma unroll
        for (int off = 32; off > 0; off >>= 1) v += __shfl_down(v, off, 64);
        acc[k] = v;
    }
    int wave = tid >> 6, lane = tid & 63;
    if (lane == 0) {
        #pragma unroll
        for (int k = 0; k < 6; ++k) red[wave * 6 + k] = acc[k];
    }
    __syncthreads();
    if (tid == 0) {
        double s[6];
        #pragma unroll
        for (int k = 0; k < 6; ++k) s[k] = red[k] + red[6 + k] + red[12 + k] + red[18 + k];
        double A = s[0], Bv = s[1], Cv = s[2], D = s[3], E = s[4], F = s[5];
        double num = A - D / 225.0;
        double varI = Bv - E / 225.0;
        double varJ = Cv - F / 225.0;
        double cc = num / sqrt(varI * varJ);
        out[0] = (float)(-cc);
    }
}

extern "C" void kernel_launch(void* const* d_in, const int* in_sizes, int n_in,
                              void* d_out, int out_size, void* d_ws, size_t ws_size,
                              hipStream_t stream) {
    const float* I = (const float*)d_in[0];
    const float* J = (const float*)d_in[1];
    float* partials = (float*)d_ws;   // 6*NBLK floats = 48 KB, SoA

    dim3 grid(NTX, NTY, NB);
    ncc_main<<<grid, 256, 0, stream>>>(I, J, partials);
    ncc_finalize<<<1, 256, 0, stream>>>(partials, (float*)d_out);
}